// Round 3
// baseline (200.009 us; speedup 1.0000x reference)
//
#include <hip/hip_runtime.h>
#include <math.h>

// Problem constants (match reference)
constexpr int   B       = 2048;
constexpr int   P       = 4;
constexpr int   D       = 256;       // K of the GEMM
constexpr int   NNEG    = 32768;
constexpr int   NTILES  = NNEG / 64; // per-row exp2-sum partials (64-col patches)
constexpr float TEMP    = 0.05f;
constexpr float ALPHA   = 0.1f;
constexpr float EPS     = 1e-12f;
constexpr float INV_T   = 1.0f / TEMP;
// A-side rows are pre-scaled by (1/T)*log2(e) so the MFMA accumulator is
// directly q = sim/T * log2(e), and exp(sim/T) = exp2(q).
constexpr float SCALE_Q = 28.853900817779268f;

typedef __bf16 bf16x8 __attribute__((ext_vector_type(8)));
typedef float  f32x4  __attribute__((ext_vector_type(4)));

// fp32 -> bf16 (RNE), bit-level
__device__ inline unsigned short f2bf(float f) {
  unsigned int u = __float_as_uint(f);
  u = (u + 0x7fffu + ((u >> 16) & 1u)) >> 16;
  return (unsigned short)u;
}

// ---------------------------------------------------------------------------
// Kernel 1: fused L2-normalize + cast to bf16 for anchors (scaled by SCALE_Q)
// and negatives (unit norm).  One wave per row; rows [0,B) -> anchors,
// [B, B+NNEG) -> negatives.  Thread (0,0) also zeroes the loss accumulator
// and ticket counter used by kernel 4 (stream order guarantees visibility).
// ---------------------------------------------------------------------------
__global__ void norm_cast_all_kernel(const float* __restrict__ a,
                                     const float* __restrict__ n,
                                     unsigned short* __restrict__ a_bf,
                                     unsigned short* __restrict__ n_bf,
                                     float* __restrict__ loss_acc,
                                     unsigned int* __restrict__ ticket) {
  if (blockIdx.x == 0 && threadIdx.x == 0) { *loss_acc = 0.0f; *ticket = 0u; }
  int w    = (blockIdx.x * blockDim.x + threadIdx.x) >> 6;
  int lane = threadIdx.x & 63;
  if (w >= B + NNEG) return;
  const float* src; unsigned short* dst; float post;
  if (w < B) { src = a + (size_t)w * D;       dst = a_bf + (size_t)w * D;       post = SCALE_Q; }
  else       { src = n + (size_t)(w - B) * D; dst = n_bf + (size_t)(w - B) * D; post = 1.0f; }
  float4 v = ((const float4*)src)[lane];
  float ss = v.x * v.x + v.y * v.y + v.z * v.z + v.w * v.w;
#pragma unroll
  for (int off = 32; off > 0; off >>= 1) ss += __shfl_xor(ss, off, 64);
  float inv = post / fmaxf(sqrtf(ss), EPS);
  ushort4 o;
  o.x = f2bf(v.x * inv); o.y = f2bf(v.y * inv);
  o.z = f2bf(v.z * inv); o.w = f2bf(v.w * inv);
  ((ushort4*)dst)[lane] = o;
}

// ---------------------------------------------------------------------------
// Kernel 2: pos_sim[b][j] exact fp32 (units: sim/T, natural-log domain).
// ---------------------------------------------------------------------------
__global__ void possim_kernel(const float* __restrict__ a,
                              const float* __restrict__ p,
                              float* __restrict__ pos_sim) {
  int w    = (blockIdx.x * blockDim.x + threadIdx.x) >> 6;  // 0..B*P-1
  int lane = threadIdx.x & 63;
  if (w >= B * P) return;
  int b = w >> 2;  // P == 4
  float4 av = ((const float4*)(a + (size_t)b * D))[lane];
  float4 pv = ((const float4*)(p + (size_t)w * D))[lane];
  float d  = av.x * pv.x + av.y * pv.y + av.z * pv.z + av.w * pv.w;
  float sa = av.x * av.x + av.y * av.y + av.z * av.z + av.w * av.w;
  float sp = pv.x * pv.x + pv.y * pv.y + pv.z * pv.z + pv.w * pv.w;
#pragma unroll
  for (int off = 32; off > 0; off >>= 1) {
    d  += __shfl_xor(d, off, 64);
    sa += __shfl_xor(sa, off, 64);
    sp += __shfl_xor(sp, off, 64);
  }
  if (lane == 0) {
    float inva = 1.0f / fmaxf(sqrtf(sa), EPS);
    float invp = 1.0f / fmaxf(sqrtf(sp), EPS);
    pos_sim[w] = d * inva * invp * INV_T;
  }
}

// ---------------------------------------------------------------------------
// Kernel 3: bf16 MFMA GEMM fused with exp2-sum partials.
// 128x128 tile, 4 waves (2x2), each wave 64x64 = 4x4 mfma_f32_16x16x32_bf16.
// BK=64, K=256 -> 4 iterations, global->LDS via global_load_lds width=16.
//
// LDS bank-conflict fix: global_load_lds forces LDS dest = base + lane*16,
// so we permute the SOURCE: lane (lrow=l>>3, cs=l&7) fetches global 16B-chunk
// (cs ^ lrow) of row lrow.  Hence chunk c of row r sits at LDS position
// c ^ (r&7); ds_read addresses use p = chunk ^ (lane&7) (row&7 == lane&7 for
// all fragment reads).  Banks are then uniformly spread (8 lanes per 4-bank
// group = minimum for b128) instead of 16-way conflicted.
//
// Epilogue: acc already holds q = sim/T*log2e (A pre-scaled); no max needed
// since |q| <= ~29 (exp2 in [4e-9, 5e8], fp32-safe).  Per row: sum of
// exp2(q) over the wave's 64 cols via 16-lane shuffle reduce -> part_s.
// ---------------------------------------------------------------------------
constexpr int BM = 128, BN = 128, BK = 64;

__global__ __launch_bounds__(256) void negsim_mfma_kernel(
    const unsigned short* __restrict__ Abf,  // [B][D] normalized*SCALE_Q bf16
    const unsigned short* __restrict__ Nbf,  // [NNEG][D] normalized bf16
    float* __restrict__ part_s) {            // [B][NTILES]
  __shared__ unsigned short As[BM * BK];  // 16 KB
  __shared__ unsigned short Bs[BN * BK];  // 16 KB

  const int tid  = threadIdx.x;
  const int wave = tid >> 6;
  const int lane = tid & 63;
  const int wx   = wave & 1;   // N direction
  const int wy   = wave >> 1;  // M direction
  const int m0   = blockIdx.y * BM;
  const int n0   = blockIdx.x * BN;

  const int lrow = lane >> 3;                    // 0..7
  const int scol = ((lane & 7) ^ lrow) * 8;      // swizzled source k-chunk

  f32x4 acc[4][4] = {};

  for (int k0 = 0; k0 < D; k0 += BK) {
#pragma unroll
    for (int i = 0; i < 4; i++) {
      const int r0 = (wave * 4 + i) * 8;
      __builtin_amdgcn_global_load_lds(
          (const __attribute__((address_space(1))) unsigned int*)
              (Abf + (size_t)(m0 + r0 + lrow) * D + k0 + scol),
          (__attribute__((address_space(3))) unsigned int*)(As + r0 * BK),
          16, 0, 0);
      __builtin_amdgcn_global_load_lds(
          (const __attribute__((address_space(1))) unsigned int*)
              (Nbf + (size_t)(n0 + r0 + lrow) * D + k0 + scol),
          (__attribute__((address_space(3))) unsigned int*)(Bs + r0 * BK),
          16, 0, 0);
    }
    __syncthreads();

#pragma unroll
    for (int kk = 0; kk < BK; kk += 32) {
      // logical chunk = kk/8 + quad; LDS position = chunk ^ (row&7),
      // and row&7 == lane&7 for every fragment row we read.
      const int p  = (((kk >> 3) + (lane >> 4)) ^ (lane & 7)) * 8;
      bf16x8 af[4], bfr[4];
#pragma unroll
      for (int mi = 0; mi < 4; mi++)
        af[mi] = *(const bf16x8*)&As[(wy * 64 + mi * 16 + (lane & 15)) * BK + p];
#pragma unroll
      for (int ni = 0; ni < 4; ni++)
        bfr[ni] = *(const bf16x8*)&Bs[(wx * 64 + ni * 16 + (lane & 15)) * BK + p];
#pragma unroll
      for (int mi = 0; mi < 4; mi++)
#pragma unroll
        for (int ni = 0; ni < 4; ni++)
          acc[mi][ni] = __builtin_amdgcn_mfma_f32_16x16x32_bf16(
              af[mi], bfr[ni], acc[mi][ni], 0, 0, 0);
    }
    __syncthreads();
  }

  // Epilogue: C/D layout row = mi*16 + (lane>>4)*4 + r, col = ni*16+(lane&15).
#pragma unroll
  for (int mi = 0; mi < 4; mi++) {
#pragma unroll
    for (int r = 0; r < 4; r++) {
      float s = __builtin_amdgcn_exp2f(acc[mi][0][r]) +
                __builtin_amdgcn_exp2f(acc[mi][1][r]) +
                __builtin_amdgcn_exp2f(acc[mi][2][r]) +
                __builtin_amdgcn_exp2f(acc[mi][3][r]);
#pragma unroll
      for (int off = 1; off < 16; off <<= 1) s += __shfl_xor(s, off, 64);
      if ((lane & 15) == 0) {
        int row = m0 + wy * 64 + mi * 16 + (lane >> 4) * 4 + r;
        part_s[(size_t)row * NTILES + (blockIdx.x * 2 + wx)] = s;
      }
    }
  }
}

// ---------------------------------------------------------------------------
// Kernel 4: per-anchor combine + loss, fused finalize via ticket pattern.
// One wave per anchor: sum 512 exp2 partials -> neg_lse = log(S); pair losses
// + weighted-pos term; atomicAdd into loss_acc; last block writes out[0].
// ---------------------------------------------------------------------------
__global__ void combine_finalize_kernel(const float* __restrict__ part_s,
                                        const float* __restrict__ pos_sim,
                                        const int* __restrict__ counts,
                                        float* __restrict__ loss_acc,
                                        unsigned int* __restrict__ ticket,
                                        float* __restrict__ out) {
  const int b    = blockIdx.x;
  const int lane = threadIdx.x;  // 64 threads
  const float* ps = part_s + (size_t)b * NTILES;
  float s = 0.0f;
#pragma unroll
  for (int i = 0; i < NTILES / 64; i++) s += ps[lane + i * 64];
#pragma unroll
  for (int off = 32; off > 0; off >>= 1) s += __shfl_xor(s, off, 64);

  if (lane == 0) {
    float L = logf(s);  // neg_lse in natural-log units
    float p0 = pos_sim[b * P + 0], p1 = pos_sim[b * P + 1];
    float p2 = pos_sim[b * P + 2], p3 = pos_sim[b * P + 3];
    int cnt = counts[b];
    float pj[P] = {p0, p1, p2, p3};
    float acc = 0.0f;
#pragma unroll
    for (int j = 0; j < P; j++) {
      if (j < cnt) {
        float hi = fmaxf(pj[j], L), lo = fminf(pj[j], L);
        acc += hi + log1pf(__expf(lo - hi)) - pj[j];
      }
    }
    float mp = fmaxf(fmaxf(p0, p1), fmaxf(p2, p3));
    float e0 = __expf(p0 - mp), e1 = __expf(p1 - mp);
    float e2 = __expf(p2 - mp), e3 = __expf(p3 - mp);
    float se = e0 + e1 + e2 + e3;
    float wps = (e0 * p0 + e1 * p1 + e2 * p2 + e3 * p3) / se;
    if (cnt > 1) {
      float hi = fmaxf(wps, L), lo = fminf(wps, L);
      acc += ALPHA * (hi + log1pf(__expf(lo - hi)) - wps);
    }
    atomicAdd(loss_acc, acc);
    __threadfence();
    unsigned int t = atomicAdd(ticket, 1u);
    if (t == (unsigned int)gridDim.x - 1u) {
      float total = atomicAdd(loss_acc, 0.0f);  // atomic read-back of final sum
      out[0] = total / (float)B;
    }
  }
}

// ---------------------------------------------------------------------------
extern "C" void kernel_launch(void* const* d_in, const int* in_sizes, int n_in,
                              void* d_out, int out_size, void* d_ws,
                              size_t ws_size, hipStream_t stream) {
  const float* anc    = (const float*)d_in[0];
  const float* pos    = (const float*)d_in[1];
  const float* neg    = (const float*)d_in[2];
  const int*   counts = (const int*)d_in[3];
  float* out = (float*)d_out;

  // Workspace layout: ~21.1 MB
  unsigned short* a_bf = (unsigned short*)d_ws;          // B*D      (1 MB)
  unsigned short* n_bf = a_bf + (size_t)B * D;           // NNEG*D   (16 MB)
  float* part_s  = (float*)(n_bf + (size_t)NNEG * D);    // B*NTILES (4 MB)
  float* pos_sim = part_s + (size_t)B * NTILES;          // B*P
  float* loss_acc = pos_sim + B * P;                     // 1
  unsigned int* ticket = (unsigned int*)(loss_acc + 1);  // 1

  norm_cast_all_kernel<<<(B + NNEG) / 4, 256, 0, stream>>>(
      anc, neg, a_bf, n_bf, loss_acc, ticket);
  possim_kernel<<<B * P / 4, 256, 0, stream>>>(anc, pos, pos_sim);

  dim3 grid(NNEG / BN, B / BM);  // (256, 16) = 4096 blocks
  negsim_mfma_kernel<<<grid, 256, 0, stream>>>(a_bf, n_bf, part_s);

  combine_finalize_kernel<<<B, 64, 0, stream>>>(part_s, pos_sim, counts,
                                                loss_acc, ticket, out);
}

// Round 4
// 163.714 us; speedup vs baseline: 1.2217x; 1.2217x over previous
//
#include <hip/hip_runtime.h>
#include <math.h>

// Problem constants (match reference)
constexpr int   B       = 2048;
constexpr int   P       = 4;
constexpr int   D       = 256;       // K of the GEMM
constexpr int   NNEG    = 32768;
constexpr int   NTILES  = NNEG / 64; // per-row exp2-sum partials (64-col patches)
constexpr float TEMP    = 0.05f;
constexpr float ALPHA   = 0.1f;
constexpr float EPS     = 1e-12f;
constexpr float INV_T   = 1.0f / TEMP;
// A-side rows are pre-scaled by (1/T)*log2(e) so the MFMA accumulator is
// directly q = sim/T * log2(e), and exp(sim/T) = exp2(q).  |q| <= ~30 so no
// max-tracking is needed (exp2 stays in fp32 range).
constexpr float SCALE_Q = 28.853900817779268f;

typedef __bf16 bf16x8 __attribute__((ext_vector_type(8)));
typedef float  f32x4  __attribute__((ext_vector_type(4)));

// fp32 -> bf16 (RNE), bit-level
__device__ inline unsigned short f2bf(float f) {
  unsigned int u = __float_as_uint(f);
  u = (u + 0x7fffu + ((u >> 16) & 1u)) >> 16;
  return (unsigned short)u;
}

// ---------------------------------------------------------------------------
// Kernel 1: fused L2-normalize + cast to bf16 for anchors (scaled by SCALE_Q)
// and negatives (unit norm).  One wave per row.
// ---------------------------------------------------------------------------
__global__ void norm_cast_all_kernel(const float* __restrict__ a,
                                     const float* __restrict__ n,
                                     unsigned short* __restrict__ a_bf,
                                     unsigned short* __restrict__ n_bf) {
  int w    = (blockIdx.x * blockDim.x + threadIdx.x) >> 6;
  int lane = threadIdx.x & 63;
  if (w >= B + NNEG) return;
  const float* src; unsigned short* dst; float post;
  if (w < B) { src = a + (size_t)w * D;       dst = a_bf + (size_t)w * D;       post = SCALE_Q; }
  else       { src = n + (size_t)(w - B) * D; dst = n_bf + (size_t)(w - B) * D; post = 1.0f; }
  float4 v = ((const float4*)src)[lane];
  float ss = v.x * v.x + v.y * v.y + v.z * v.z + v.w * v.w;
#pragma unroll
  for (int off = 32; off > 0; off >>= 1) ss += __shfl_xor(ss, off, 64);
  float inv = post / fmaxf(sqrtf(ss), EPS);
  ushort4 o;
  o.x = f2bf(v.x * inv); o.y = f2bf(v.y * inv);
  o.z = f2bf(v.z * inv); o.w = f2bf(v.w * inv);
  ((ushort4*)dst)[lane] = o;
}

// ---------------------------------------------------------------------------
// Kernel 2: pos_sim[b][j] exact fp32 (units: sim/T, natural-log domain).
// ---------------------------------------------------------------------------
__global__ void possim_kernel(const float* __restrict__ a,
                              const float* __restrict__ p,
                              float* __restrict__ pos_sim) {
  int w    = (blockIdx.x * blockDim.x + threadIdx.x) >> 6;  // 0..B*P-1
  int lane = threadIdx.x & 63;
  if (w >= B * P) return;
  int b = w >> 2;  // P == 4
  float4 av = ((const float4*)(a + (size_t)b * D))[lane];
  float4 pv = ((const float4*)(p + (size_t)w * D))[lane];
  float d  = av.x * pv.x + av.y * pv.y + av.z * pv.z + av.w * pv.w;
  float sa = av.x * av.x + av.y * av.y + av.z * av.z + av.w * av.w;
  float sp = pv.x * pv.x + pv.y * pv.y + pv.z * pv.z + pv.w * pv.w;
#pragma unroll
  for (int off = 32; off > 0; off >>= 1) {
    d  += __shfl_xor(d, off, 64);
    sa += __shfl_xor(sa, off, 64);
    sp += __shfl_xor(sp, off, 64);
  }
  if (lane == 0) {
    float inva = 1.0f / fmaxf(sqrtf(sa), EPS);
    float invp = 1.0f / fmaxf(sqrtf(sp), EPS);
    pos_sim[w] = d * inva * invp * INV_T;
  }
}

// ---------------------------------------------------------------------------
// Kernel 3: bf16 MFMA GEMM fused with exp2-sum partials.
// 128x128 tile, 4 waves (2x2), each wave 64x64 = 4x4 mfma_f32_16x16x32_bf16.
// BK=64, K=256 -> 4 iterations.
//
// DOUBLE-BUFFERED staging (2 x 32 KB = 64 KB LDS): the prefetch for iter i+1
// is issued AFTER the barrier at the top of iter i, so the compiler's
// mandatory `s_waitcnt vmcnt(0)` before the NEXT s_barrier waits on loads
// that have had a full compute phase (~800 cyc) in flight -> latency hidden,
// and only ONE barrier per K-iter.  Safe: stage(i+1) overwrites the buffer
// whose readers (iter i-1) all passed the current barrier.
//
// LDS bank-conflict fix (XOR swizzle via SOURCE permutation): global_load_lds
// forces LDS dest = base + lane*16, so lane (lrow=l>>3, cs=l&7) fetches
// global 16B-chunk (cs ^ lrow) of row lrow; chunk c of row r sits at LDS
// position c ^ (r&7).  Fragment reads use p = chunk ^ (lane&7) since
// row&7 == lane&7 for every fragment row.  Measured: conflicts 1.26e7 -> 0.
//
// Epilogue: acc already holds q = sim/T*log2e; per row, sum exp2(q) over the
// wave's 64 cols via 16-lane shuffle reduce -> part_s (no max needed).
// ---------------------------------------------------------------------------
constexpr int BM = 128, BN = 128, BK = 64;

__global__ __launch_bounds__(256) void negsim_mfma_kernel(
    const unsigned short* __restrict__ Abf,  // [B][D] normalized*SCALE_Q bf16
    const unsigned short* __restrict__ Nbf,  // [NNEG][D] normalized bf16
    float* __restrict__ part_s) {            // [B][NTILES]
  __shared__ unsigned short As[2][BM * BK];  // 2 x 16 KB
  __shared__ unsigned short Bs[2][BN * BK];  // 2 x 16 KB  (total 64 KB)

  const int tid  = threadIdx.x;
  const int wave = tid >> 6;
  const int lane = tid & 63;
  const int wx   = wave & 1;   // N direction
  const int wy   = wave >> 1;  // M direction
  const int m0   = blockIdx.y * BM;
  const int n0   = blockIdx.x * BN;

  const int lrow = lane >> 3;                    // 0..7
  const int scol = ((lane & 7) ^ lrow) * 8;      // swizzled source k-chunk

  f32x4 acc[4][4] = {};

  // stage K-block k0 into buffer `buf`
  auto stage = [&](int k0, int buf) {
#pragma unroll
    for (int i = 0; i < 4; i++) {
      const int r0 = (wave * 4 + i) * 8;
      __builtin_amdgcn_global_load_lds(
          (const __attribute__((address_space(1))) unsigned int*)
              (Abf + (size_t)(m0 + r0 + lrow) * D + k0 + scol),
          (__attribute__((address_space(3))) unsigned int*)(&As[buf][r0 * BK]),
          16, 0, 0);
      __builtin_amdgcn_global_load_lds(
          (const __attribute__((address_space(1))) unsigned int*)
              (Nbf + (size_t)(n0 + r0 + lrow) * D + k0 + scol),
          (__attribute__((address_space(3))) unsigned int*)(&Bs[buf][r0 * BK]),
          16, 0, 0);
    }
  };

  stage(0, 0);

#pragma unroll
  for (int it = 0; it < D / BK; it++) {
    __syncthreads();                 // drains stage(it) (issued 1 phase ago)
    if (it + 1 < D / BK) stage((it + 1) * BK, (it + 1) & 1);
    const unsigned short* Ab = As[it & 1];
    const unsigned short* Bb = Bs[it & 1];
#pragma unroll
    for (int kk = 0; kk < BK; kk += 32) {
      const int p = (((kk >> 3) + (lane >> 4)) ^ (lane & 7)) * 8;
      bf16x8 af[4], bfr[4];
#pragma unroll
      for (int mi = 0; mi < 4; mi++)
        af[mi] = *(const bf16x8*)&Ab[(wy * 64 + mi * 16 + (lane & 15)) * BK + p];
#pragma unroll
      for (int ni = 0; ni < 4; ni++)
        bfr[ni] = *(const bf16x8*)&Bb[(wx * 64 + ni * 16 + (lane & 15)) * BK + p];
#pragma unroll
      for (int mi = 0; mi < 4; mi++)
#pragma unroll
        for (int ni = 0; ni < 4; ni++)
          acc[mi][ni] = __builtin_amdgcn_mfma_f32_16x16x32_bf16(
              af[mi], bfr[ni], acc[mi][ni], 0, 0, 0);
    }
  }

  // Epilogue: C/D layout row = mi*16 + (lane>>4)*4 + r, col = ni*16+(lane&15).
#pragma unroll
  for (int mi = 0; mi < 4; mi++) {
#pragma unroll
    for (int r = 0; r < 4; r++) {
      float s = __builtin_amdgcn_exp2f(acc[mi][0][r]) +
                __builtin_amdgcn_exp2f(acc[mi][1][r]) +
                __builtin_amdgcn_exp2f(acc[mi][2][r]) +
                __builtin_amdgcn_exp2f(acc[mi][3][r]);
#pragma unroll
      for (int off = 1; off < 16; off <<= 1) s += __shfl_xor(s, off, 64);
      if ((lane & 15) == 0) {
        int row = m0 + wy * 64 + mi * 16 + (lane >> 4) * 4 + r;
        part_s[(size_t)row * NTILES + (blockIdx.x * 2 + wx)] = s;
      }
    }
  }
}

// ---------------------------------------------------------------------------
// Kernel 4: per-anchor loss -> loss[b].  One wave per anchor, NO atomics
// (2048 serialized atomicAdds to one address cost 56 us in round 3).
// ---------------------------------------------------------------------------
__global__ void anchor_loss_kernel(const float* __restrict__ part_s,
                                   const float* __restrict__ pos_sim,
                                   const int* __restrict__ counts,
                                   float* __restrict__ loss) {
  int b    = (blockIdx.x * blockDim.x + threadIdx.x) >> 6;
  int lane = threadIdx.x & 63;
  if (b >= B) return;
  const float* ps = part_s + (size_t)b * NTILES;
  float s = 0.0f;
#pragma unroll
  for (int i = 0; i < NTILES / 64; i++) s += ps[lane + i * 64];
#pragma unroll
  for (int off = 32; off > 0; off >>= 1) s += __shfl_xor(s, off, 64);

  if (lane == 0) {
    float L = logf(s);  // neg_lse in natural-log units
    float p0 = pos_sim[b * P + 0], p1 = pos_sim[b * P + 1];
    float p2 = pos_sim[b * P + 2], p3 = pos_sim[b * P + 3];
    int cnt = counts[b];
    float pj[P] = {p0, p1, p2, p3};
    float acc = 0.0f;
#pragma unroll
    for (int j = 0; j < P; j++) {
      if (j < cnt) {
        float hi = fmaxf(pj[j], L), lo = fminf(pj[j], L);
        acc += hi + log1pf(__expf(lo - hi)) - pj[j];
      }
    }
    float mp = fmaxf(fmaxf(p0, p1), fmaxf(p2, p3));
    float e0 = __expf(p0 - mp), e1 = __expf(p1 - mp);
    float e2 = __expf(p2 - mp), e3 = __expf(p3 - mp);
    float se = e0 + e1 + e2 + e3;
    float wps = (e0 * p0 + e1 * p1 + e2 * p2 + e3 * p3) / se;
    if (cnt > 1) {
      float hi = fmaxf(wps, L), lo = fminf(wps, L);
      acc += ALPHA * (hi + log1pf(__expf(lo - hi)) - wps);
    }
    loss[b] = acc;
  }
}

// ---------------------------------------------------------------------------
// Kernel 5: final reduce over loss[B] -> out[0] = sum / B.  Single block.
// ---------------------------------------------------------------------------
__global__ void final_reduce_kernel(const float* __restrict__ loss,
                                    float* __restrict__ out) {
  const int tid = threadIdx.x;
  float acc = 0.0f;
  for (int i = tid; i < B; i += 256) acc += loss[i];
#pragma unroll
  for (int off = 32; off > 0; off >>= 1) acc += __shfl_xor(acc, off, 64);
  __shared__ float sa[4];
  int wid = tid >> 6, lane = tid & 63;
  if (lane == 0) sa[wid] = acc;
  __syncthreads();
  if (tid == 0) out[0] = (sa[0] + sa[1] + sa[2] + sa[3]) / (float)B;
}

// ---------------------------------------------------------------------------
extern "C" void kernel_launch(void* const* d_in, const int* in_sizes, int n_in,
                              void* d_out, int out_size, void* d_ws,
                              size_t ws_size, hipStream_t stream) {
  const float* anc    = (const float*)d_in[0];
  const float* pos    = (const float*)d_in[1];
  const float* neg    = (const float*)d_in[2];
  const int*   counts = (const int*)d_in[3];
  float* out = (float*)d_out;

  // Workspace layout: ~21.1 MB
  unsigned short* a_bf = (unsigned short*)d_ws;          // B*D      (1 MB)
  unsigned short* n_bf = a_bf + (size_t)B * D;           // NNEG*D   (16 MB)
  float* part_s  = (float*)(n_bf + (size_t)NNEG * D);    // B*NTILES (4 MB)
  float* pos_sim = part_s + (size_t)B * NTILES;          // B*P
  float* loss    = pos_sim + B * P;                      // B

  norm_cast_all_kernel<<<(B + NNEG) / 4, 256, 0, stream>>>(anc, neg, a_bf, n_bf);
  possim_kernel<<<B * P / 4, 256, 0, stream>>>(anc, pos, pos_sim);

  dim3 grid(NNEG / BN, B / BM);  // (256, 16) = 4096 blocks
  negsim_mfma_kernel<<<grid, 256, 0, stream>>>(a_bf, n_bf, part_s);

  anchor_loss_kernel<<<B / 4, 256, 0, stream>>>(part_s, pos_sim, counts, loss);
  final_reduce_kernel<<<1, 256, 0, stream>>>(loss, out);
}